// Round 11
// baseline (129.353 us; speedup 1.0000x reference)
//
#include <hip/hip_runtime.h>

// B=16, N=1024, D=512, DIRECTIONS=2
#define NB 16
#define NN 1024
#define ND 512

typedef __attribute__((ext_vector_type(8))) short short8;   // 8 x bf16
typedef __attribute__((ext_vector_type(4))) float f32x4;

typedef const __attribute__((address_space(1))) void* gptr1;
typedef __attribute__((address_space(3))) void* lptr3;

#define VMCNT0() asm volatile("s_waitcnt vmcnt(0)" ::: "memory")
#define VMCNT4() asm volatile("s_waitcnt vmcnt(4)" ::: "memory")
#define VMCNT8() asm volatile("s_waitcnt vmcnt(8)" ::: "memory")
#define LGKM0()  asm volatile("s_waitcnt lgkmcnt(0)" ::: "memory")
#define BAR()    __builtin_amdgcn_s_barrier()
#define SCHED0() __builtin_amdgcn_sched_barrier(0)

union U8 { uint4 u; short8 s; };

static __device__ __forceinline__ unsigned f2bf(float f) {
  union { float f; unsigned u; } v; v.f = f;
  unsigned r = v.u + 0x7FFFu + ((v.u >> 16) & 1u);   // RNE
  return r >> 16;
}
static __device__ __forceinline__ float bf2f(unsigned short h) {
  union { unsigned u; float f; } v; v.u = ((unsigned)h) << 16;
  return v.f;
}

// ---- k_wtcat: W [1024][512] f32 -> WTcat [1024 r][512 c] bf16 ---------------
__global__ void k_wtcat(const float* __restrict__ W, unsigned short* __restrict__ WTcat) {
  __shared__ float t[64][65];
  int dir = blockIdx.z;
  int r0 = blockIdx.x * 64;   // c (W row within half)
  int c0 = blockIdx.y * 64;   // d
  int tid = threadIdx.x;
#pragma unroll
  for (int i = 0; i < 4; ++i) {
    int f = i * 256 + tid;
    int r = f >> 4, cq = f & 15;
    float4 v = *(const float4*)(W + (size_t)(dir * 512 + r0 + r) * ND + c0 + cq * 4);
    t[r][cq * 4 + 0] = v.x; t[r][cq * 4 + 1] = v.y;
    t[r][cq * 4 + 2] = v.z; t[r][cq * 4 + 3] = v.w;
  }
  __syncthreads();
#pragma unroll
  for (int i = 0; i < 8; ++i) {
    int f = i * 256 + tid;
    int oc = f >> 5;            // d-local
    int on = (f & 31) * 2;      // c-local pair
    unsigned lo = f2bf(t[on][oc]), hi = f2bf(t[on + 1][oc]);
    *(unsigned*)(WTcat + (size_t)(dir * 512 + c0 + oc) * ND + r0 + on) = lo | (hi << 16);
  }
}

// ---- k_pack: adj -> 2-bit codes. Word w (m=16w..16w+15) stored at permuted
// position (w&~7) | ((w&1)<<2) | ((w>>1)&3), so one uint4 at group*8 + h2*4
// holds words {2ks + h2} of the group, ks=0..3 (one BK=128 kt). Also counts.
__global__ void k_pack(const int* __restrict__ adj, unsigned* __restrict__ packed,
                       float* __restrict__ invc) {
  int wid = threadIdx.x >> 6, lane = threadIdx.x & 63;
  int wrow0 = (blockIdx.x * 4 + wid) * 4;
  int pl = (lane & ~7) | ((lane & 1) << 2) | ((lane >> 1) & 3);
#pragma unroll
  for (int r = 0; r < 4; ++r) {
    int row = wrow0 + r;
    const int* p = adj + (size_t)row * NN + lane * 16;
    unsigned u = 0;
#pragma unroll
    for (int i = 0; i < 4; ++i) {
      int4 v = *(const int4*)(p + i * 4);
      u |= ((unsigned)v.x << (8 * i)) | ((unsigned)v.y << (8 * i + 2))
         | ((unsigned)v.z << (8 * i + 4)) | ((unsigned)v.w << (8 * i + 6));
    }
    packed[(size_t)row * 64 + pl] = u;
    unsigned c1 = __popc(u & 0x55555555u);
    unsigned c2 = __popc(u & 0xAAAAAAAAu);
    unsigned pr = c1 | (c2 << 16);
#pragma unroll
    for (int o = 32; o; o >>= 1) pr += __shfl_xor(pr, o);
    if (lane == 0) {
      invc[row * 2 + 0] = 1.0f / ((float)(pr & 0xFFFFu) + 1e-13f);
      invc[row * 2 + 1] = 1.0f / ((float)(pr >> 16) + 1e-13f);
    }
  }
}

// ---- k_pre: Ptcat[b][r][m] = bf16( sum_c WTcat[r][c] * hid[b][m][c] ) -------
// M=1024 (r), N=1024 (m), K=512. BM=BN=128, BK=64.
// Single barrier per kt: A DMA-dbuf, B (converted hid) ds-write-dbuf.
__global__ __launch_bounds__(256, 2) void k_pre(
    const float* __restrict__ hid, const unsigned short* __restrict__ WTcat,
    unsigned short* __restrict__ Ptcat) {
  __shared__ __align__(16) char smem[65536];   // A 2x16KB @0; B 2x16KB @32768

  int phys = blockIdx.x;                       // 1024 blocks
  int logical = (phys & 7) * 128 + (phys >> 3);
  int b = logical >> 6;
  int rem = logical & 63;
  int rt = rem >> 3, mt = rem & 7;
  int r0 = rt * 128, m0 = mt * 128;

  int tid = threadIdx.x, lane = tid & 63, wid = tid >> 6;
  int wr = wid >> 1, wc = wid & 1;
  int l15 = lane & 15, lq = lane >> 4;
  int srow = lane >> 3;
  int ssl = (lane & 7) ^ srow;

  const float* hb = hid + (size_t)b * NN * ND;

  f32x4 acc[4][4];
  f32x4 zero = {0.f, 0.f, 0.f, 0.f};
#pragma unroll
  for (int i = 0; i < 4; ++i)
#pragma unroll
    for (int j = 0; j < 4; ++j) acc[i][j] = zero;

  float4 fA[8], fB[8];
  // prologue: fA = hid(0); DMA(0)->A0; convert fA->B0; fB = hid(1)
#pragma unroll
  for (int it = 0; it < 8; ++it) {
    int f = it * 256 + tid;
    fA[it] = *(const float4*)(hb + (size_t)(m0 + (f >> 4)) * ND + (f & 15) * 4);
  }
#pragma unroll
  for (int i = 0; i < 4; ++i) {
    int q = wid * 4 + i;
    __builtin_amdgcn_global_load_lds((gptr1)(WTcat + (size_t)(r0 + q * 8 + srow) * ND + ssl * 8),
                                     (lptr3)(smem + q * 1024), 16, 0, 0);
  }
#pragma unroll
  for (int it = 0; it < 8; ++it) {
    int f = it * 256 + tid;
    int row = f >> 4, c4 = f & 15;
    float4 v = fA[it];
    unsigned lo = f2bf(v.x) | (f2bf(v.y) << 16);
    unsigned hi = f2bf(v.z) | (f2bf(v.w) << 16);
    int addr = row * 128 + (((c4 >> 1) ^ (row & 7)) * 16) + (c4 & 1) * 8;
    *(uint2*)(smem + 32768 + addr) = make_uint2(lo, hi);
  }
#pragma unroll
  for (int it = 0; it < 8; ++it) {
    int f = it * 256 + tid;
    fB[it] = *(const float4*)(hb + (size_t)(m0 + (f >> 4)) * ND + 64 + (f & 15) * 4);
  }
  LGKM0(); VMCNT8();             // A-DMA(0) done; fB stays in flight

// body kt: FCUR holds hid(kt+1) (to convert), FNXT receives hid(kt+2)
#define PRE_BODY(KT_, FCUR, FNXT)                                             \
  {                                                                           \
    int kt = (KT_);                                                           \
    BAR();                                                                    \
    if (kt < 7) {                                                             \
      char* ab = smem + ((~kt & 1) << 14);                                    \
      _Pragma("unroll")                                                       \
      for (int i = 0; i < 4; ++i) {                                           \
        int q = wid * 4 + i;                                                  \
        __builtin_amdgcn_global_load_lds(                                     \
          (gptr1)(WTcat + (size_t)(r0 + q * 8 + srow) * ND + (kt + 1) * 64 + ssl * 8), \
          (lptr3)(ab + q * 1024), 16, 0, 0);                                  \
      }                                                                       \
      SCHED0();                                                               \
    }                                                                         \
    const char* ac = smem + ((kt & 1) << 14);                                 \
    const char* bc = smem + 32768 + ((kt & 1) << 14);                         \
    __builtin_amdgcn_s_setprio(1);                                            \
    _Pragma("unroll")                                                         \
    for (int ks = 0; ks < 2; ++ks) {                                          \
      short8 a[4], bf[4];                                                     \
      _Pragma("unroll")                                                       \
      for (int mi = 0; mi < 4; ++mi) {                                        \
        int slot = (ks * 4 + lq) ^ (l15 & 7);                                 \
        a[mi] = *(const short8*)(ac + (wr * 64 + mi * 16 + l15) * 128 + slot * 16); \
      }                                                                       \
      _Pragma("unroll")                                                       \
      for (int nj = 0; nj < 4; ++nj) {                                        \
        int slot = (ks * 4 + lq) ^ (l15 & 7);                                 \
        bf[nj] = *(const short8*)(bc + (wc * 64 + nj * 16 + l15) * 128 + slot * 16); \
      }                                                                       \
      _Pragma("unroll")                                                       \
      for (int mi = 0; mi < 4; ++mi)                                          \
        _Pragma("unroll")                                                     \
        for (int nj = 0; nj < 4; ++nj)                                        \
          acc[mi][nj] = __builtin_amdgcn_mfma_f32_16x16x32_bf16(a[mi], bf[nj], acc[mi][nj], 0, 0, 0); \
    }                                                                         \
    __builtin_amdgcn_s_setprio(0);                                            \
    if (kt < 7) {                                                             \
      char* bn = smem + 32768 + ((~kt & 1) << 14);                            \
      _Pragma("unroll")                                                       \
      for (int it = 0; it < 8; ++it) {                                        \
        int f = it * 256 + tid;                                               \
        int row = f >> 4, c4 = f & 15;                                        \
        float4 v = FCUR[it];                                                  \
        unsigned lo = f2bf(v.x) | (f2bf(v.y) << 16);                          \
        unsigned hi = f2bf(v.z) | (f2bf(v.w) << 16);                          \
        int addr = row * 128 + (((c4 >> 1) ^ (row & 7)) * 16) + (c4 & 1) * 8; \
        *(uint2*)(bn + addr) = make_uint2(lo, hi);                            \
      }                                                                       \
    }                                                                         \
    if (kt < 6) {                                                             \
      _Pragma("unroll")                                                       \
      for (int it = 0; it < 8; ++it) {                                        \
        int f = it * 256 + tid;                                               \
        FNXT[it] = *(const float4*)(hb + (size_t)(m0 + (f >> 4)) * ND + (kt + 2) * 64 + (f & 15) * 4); \
      }                                                                       \
      LGKM0(); VMCNT8();                                                      \
    } else if (kt < 7) {                                                      \
      LGKM0(); VMCNT0();                                                      \
    }                                                                         \
  }

#pragma unroll 1
  for (int kk = 0; kk < 4; ++kk) {
    PRE_BODY(kk * 2,     fB, fA)
    PRE_BODY(kk * 2 + 1, fA, fB)
  }
#undef PRE_BODY

  unsigned short* Pb = Ptcat + (size_t)b * NN * NN;
#pragma unroll
  for (int mi = 0; mi < 4; ++mi) {
#pragma unroll
    for (int rr = 0; rr < 4; ++rr) {
      int r = r0 + wr * 64 + mi * 16 + lq * 4 + rr;
#pragma unroll
      for (int nj = 0; nj < 4; ++nj) {
        int m = m0 + wc * 64 + nj * 16 + l15;
        Pb[(size_t)r * NN + m] = (unsigned short)f2bf(acc[mi][nj][rr]);
      }
    }
  }
}

// ---- k_main: preS[n][d] = bf16(relu(i1*S1 + i2*S2 + bias) + hid) ------------
// BK=128 (16 kt, dir = kt>>3). A-masks unpacked per-lane from uint4 codes
// (ping-pong, 2-ahead); B dbuf 2x32KB (two 16KB subtiles each). 1 barrier/kt,
// vmcnt(4) counted wait.
__global__ __launch_bounds__(256, 2) void k_main(
    const unsigned* __restrict__ packed, const unsigned short* __restrict__ Ptcat,
    const float* __restrict__ invc, const float* __restrict__ bias,
    const float* __restrict__ hid, unsigned short* __restrict__ preS) {
  __shared__ __align__(16) char smB[65536];    // 2 bufs x (2 subtiles x 16KB)

  int phys = blockIdx.x;                       // 512 blocks
  int logical = (phys & 7) * 64 + (phys >> 3);
  int b = logical >> 5;
  int rem = logical & 31;
  int mt = rem >> 2, dt = rem & 3;
  int n0 = mt * 128, d0 = dt * 128;

  int tid = threadIdx.x, lane = tid & 63, wid = tid >> 6;
  int wr = wid >> 1, wc = wid & 1;
  int l15 = lane & 15, lq = lane >> 4;
  int h2 = (lq >> 1) & 1;
  int srow = lane >> 3;
  int ssl = (lane & 7) ^ srow;
  size_t bN = (size_t)b * NN;

  // codes base: per mi offset mi*16 rows = mi*1024 words
  const unsigned* cpb = packed + (bN + n0 + wr * 64 + l15) * 64 + h2 * 4;
  const unsigned short* Ptb = Ptcat + bN * NN;

  // B DMA row base (int offsets; call i covers LDS rows q*8..q*8+7, q=wid*4+i)
  int rowbase = (d0 + wid * 32 + srow) * NN + ssl * 8;
  // frag read offsets (within a 16KB subtile)
  int fo0 = (wc * 64 + l15) * 128 + ((lq ^ (l15 & 7)) * 16);
  int fo1 = (wc * 64 + l15) * 128 + (((4 + lq) ^ (l15 & 7)) * 16);

  f32x4 accA[4][4], accB[4][4];
  f32x4 zero = {0.f, 0.f, 0.f, 0.f};
#pragma unroll
  for (int i = 0; i < 4; ++i)
#pragma unroll
    for (int j = 0; j < 4; ++j) { accA[i][j] = zero; accB[i][j] = zero; }

  // prologue: codes(0) -> cA, DMA(0) -> buf0, codes(1) -> cB
  uint4 cA[4], cB[4];
#pragma unroll
  for (int mi = 0; mi < 4; ++mi) cA[mi] = *(const uint4*)(cpb + mi * 1024);
#pragma unroll
  for (int i = 0; i < 4; ++i) {
    __builtin_amdgcn_global_load_lds((gptr1)(Ptb + rowbase + i * 8192),
                                     (lptr3)(smB + (wid * 4 + i) * 1024), 16, 0, 0);
    __builtin_amdgcn_global_load_lds((gptr1)(Ptb + rowbase + i * 8192 + 64),
                                     (lptr3)(smB + 16384 + (wid * 4 + i) * 1024), 16, 0, 0);
  }
  SCHED0();
#pragma unroll
  for (int mi = 0; mi < 4; ++mi) cB[mi] = *(const uint4*)(cpb + mi * 1024 + 8);

  unsigned shb = (unsigned)((lq & 1) * 16);    // + dir, set per dir-loop

// One kt (BK=128). CSET = uint4 codes for this kt; reloaded for kt+2
// (dir-local word group: ((kt+2)&7)*8 — codes are dir-independent).
#define KT_BODY(KT_, CSET, ACC)                                               \
  {                                                                           \
    int kt = (KT_);                                                           \
    if (kt == 15) { VMCNT0(); } else { VMCNT4(); }                            \
    BAR();                                                                    \
    if (kt < 15) {                                                            \
      int t = kt + 1;                                                         \
      int koff = ((t & 7) << 7) + ((t >> 3) << 19);                           \
      char* db = smB + ((~kt & 1) << 15);                                     \
      _Pragma("unroll")                                                       \
      for (int i = 0; i < 4; ++i) {                                           \
        __builtin_amdgcn_global_load_lds((gptr1)(Ptb + rowbase + i * 8192 + koff), \
            (lptr3)(db + (wid * 4 + i) * 1024), 16, 0, 0);                    \
        __builtin_amdgcn_global_load_lds((gptr1)(Ptb + rowbase + i * 8192 + koff + 64), \
            (lptr3)(db + 16384 + (wid * 4 + i) * 1024), 16, 0, 0);            \
      }                                                                       \
      SCHED0();                                                               \
    }                                                                         \
    const char* bb = smB + ((kt & 1) << 15);                                  \
    _Pragma("unroll")                                                         \
    for (int ks = 0; ks < 4; ++ks) {                                          \
      const char* bp = bb + ((ks >> 1) << 14) + ((ks & 1) ? fo1 : fo0);       \
      short8 bf[4];                                                           \
      _Pragma("unroll")                                                       \
      for (int nj = 0; nj < 4; ++nj) bf[nj] = *(const short8*)(bp + nj * 2048); \
      U8 a[4];                                                                \
      _Pragma("unroll")                                                       \
      for (int mi = 0; mi < 4; ++mi) {                                        \
        unsigned wd = (ks == 0) ? CSET[mi].x : (ks == 1) ? CSET[mi].y         \
                     : (ks == 2) ? CSET[mi].z : CSET[mi].w;                   \
        unsigned cd = wd >> shb;                                              \
        _Pragma("unroll")                                                     \
        for (int j = 0; j < 4; ++j) {                                         \
          unsigned t5 = (cd >> (4 * j)) & 5u;                                 \
          a[mi].u[j] = ((t5 | (t5 << 14)) & 0x00010001u) * 0x3F80u;           \
        }                                                                     \
      }                                                                       \
      __builtin_amdgcn_s_setprio(1);                                          \
      _Pragma("unroll")                                                       \
      for (int nj = 0; nj < 4; ++nj)                                          \
        _Pragma("unroll")                                                     \
        for (int mi = 0; mi < 4; ++mi)                                        \
          ACC[mi][nj] = __builtin_amdgcn_mfma_f32_16x16x32_bf16(a[mi].s, bf[nj], ACC[mi][nj], 0, 0, 0); \
      __builtin_amdgcn_s_setprio(0);                                          \
    }                                                                         \
    if (kt < 14) {                                                            \
      _Pragma("unroll")                                                       \
      for (int mi = 0; mi < 4; ++mi)                                          \
        CSET[mi] = *(const uint4*)(cpb + mi * 1024 + ((kt + 2) & 7) * 8);     \
    }                                                                         \
  }

#pragma unroll 1
  for (int kk = 0; kk < 4; ++kk) {       // dir 0: kt 0..7
    KT_BODY(kk * 2,     cA, accA)
    KT_BODY(kk * 2 + 1, cB, accA)
  }
  shb = (unsigned)((lq & 1) * 16 + 1);
#pragma unroll 1
  for (int kk = 4; kk < 8; ++kk) {       // dir 1: kt 8..15
    KT_BODY(kk * 2,     cA, accB)
    KT_BODY(kk * 2 + 1, cB, accB)
  }
#undef KT_BODY

  // epilogue: f32 weights, bias, relu, residual; write pre-LN bf16
#pragma unroll
  for (int mi = 0; mi < 4; ++mi) {
#pragma unroll
    for (int rr = 0; rr < 4; ++rr) {
      int n = n0 + wr * 64 + mi * 16 + lq * 4 + rr;
      float i1 = invc[(bN + n) * 2 + 0];
      float i2 = invc[(bN + n) * 2 + 1];
      const float* hrow = hid + (bN + n) * ND;
      unsigned short* prow = preS + (bN + n) * ND;
#pragma unroll
      for (int nj = 0; nj < 4; ++nj) {
        int d = d0 + wc * 64 + nj * 16 + l15;
        float v = accA[mi][nj][rr] * i1 + accB[mi][nj][rr] * i2 + bias[d];
        v = fmaxf(v, 0.f);
        v += hrow[d];
        prow[d] = (unsigned short)f2bf(v);
      }
    }
  }
}

// ---- k_ln: rowwise LayerNorm, bf16 preS -> f32 out --------------------------
__global__ void k_ln(const unsigned short* __restrict__ preS, float* __restrict__ out,
                     const float* __restrict__ gamma, const float* __restrict__ beta) {
  int row = blockIdx.x * 4 + (threadIdx.x >> 6);
  int lane = threadIdx.x & 63;
  short8 raw = *(const short8*)(preS + (size_t)row * ND + lane * 8);
  float x[8];
#pragma unroll
  for (int i = 0; i < 8; ++i) x[i] = bf2f((unsigned short)raw[i]);
  float s = 0.f;
#pragma unroll
  for (int i = 0; i < 8; ++i) s += x[i];
#pragma unroll
  for (int o = 32; o; o >>= 1) s += __shfl_xor(s, o);
  float mu = s * (1.0f / 512.0f);
  float v = 0.f;
#pragma unroll
  for (int i = 0; i < 8; ++i) { float d = x[i] - mu; v += d * d; }
#pragma unroll
  for (int o = 32; o; o >>= 1) v += __shfl_xor(v, o);
  float rs = rsqrtf(v * (1.0f / 512.0f) + 1e-5f);
  float4 g0 = *(const float4*)(gamma + lane * 8);
  float4 g1 = *(const float4*)(gamma + lane * 8 + 4);
  float4 b0 = *(const float4*)(beta + lane * 8);
  float4 b1 = *(const float4*)(beta + lane * 8 + 4);
  float4 y0, y1;
  y0.x = (x[0] - mu) * rs * g0.x + b0.x; y0.y = (x[1] - mu) * rs * g0.y + b0.y;
  y0.z = (x[2] - mu) * rs * g0.z + b0.z; y0.w = (x[3] - mu) * rs * g0.w + b0.w;
  y1.x = (x[4] - mu) * rs * g1.x + b1.x; y1.y = (x[5] - mu) * rs * g1.y + b1.y;
  y1.z = (x[6] - mu) * rs * g1.z + b1.z; y1.w = (x[7] - mu) * rs * g1.w + b1.w;
  float* p = out + (size_t)row * ND + lane * 8;
  *(float4*)p = y0;
  *(float4*)(p + 4) = y1;
}

extern "C" void kernel_launch(void* const* d_in, const int* in_sizes, int n_in,
                              void* d_out, int out_size, void* d_ws, size_t ws_size,
                              hipStream_t stream) {
  (void)in_sizes; (void)n_in; (void)out_size; (void)ws_size;
  const int*   adj   = (const int*)d_in[0];
  const float* hid   = (const float*)d_in[1];
  const float* W     = (const float*)d_in[2];
  const float* bias  = (const float*)d_in[3];
  const float* gamma = (const float*)d_in[4];
  const float* beta  = (const float*)d_in[5];
  float* out = (float*)d_out;

  char* ws = (char*)d_ws;
  // WTcat (1 MiB, dead after k_pre) shares offset 0 with preS (written later).
  unsigned short* WTcat  = (unsigned short*)ws;                 // 1 MiB
  unsigned short* preS   = (unsigned short*)ws;                 // 16 MiB (after k_pre)
  unsigned short* Ptcat  = (unsigned short*)(ws + 16777216);    // 32 MiB
  unsigned*       packed = (unsigned*)(ws + 50331648);          // 4 MiB
  float*          invc   = (float*)(ws + 54525952);             // 128 KiB

  k_wtcat<<<dim3(8, 8, 2), 256, 0, stream>>>(W, WTcat);
  k_pack <<<1024, 256, 0, stream>>>(adj, packed, invc);
  k_pre  <<<1024, 256, 0, stream>>>(hid, WTcat, Ptcat);
  k_main <<<512, 256, 0, stream>>>(packed, Ptcat, invc, bias, hid, preS);
  k_ln   <<<4096, 256, 0, stream>>>(preS, out, gamma, beta);
}